// Round 2
// baseline (9337.640 us; speedup 1.0000x reference)
//
#include <hip/hip_runtime.h>

// LSTM: B=128, S=256, I=512, H=1024, O=512.
// bf16 MFMA persistent kernel, 128 wgs x 256 thr, hand-rolled grid barrier
// (monotone device-scope atomic counter -- deadlock-free since 128 blocks
// < 256 CUs; spinning blocks cannot starve undispatched ones).
// Each wg owns 8 hidden units x 4 gates (32 gate-columns); its Wh slice
// (32x1024 bf16 = 64 KiB) lives in LDS for all 256 steps (XOR-swizzled);
// cell state c stays in VGPRs. Per step: x-part GEMM (no h dependence)
// BEFORE the barrier wait, h-part after. One arrive/wait pair per step.

#define B_ 128
#define S_ 256
#define I_ 512
#define H_ 1024
#define O_ 512

typedef unsigned short u16;
typedef unsigned int u32;

typedef short v8s __attribute__((ext_vector_type(8)));   // 8 x bf16 (4 VGPR)
typedef float v16f __attribute__((ext_vector_type(16)));
typedef float v4f __attribute__((ext_vector_type(4)));

__device__ __forceinline__ u16 f2bf(float f) {
  u32 u = __float_as_uint(f);
  u32 r = (u + 0x7fffu + ((u >> 16) & 1u)) >> 16;   // RNE
  return (u16)r;
}
__device__ __forceinline__ u32 pack2(float a, float b) {
  return (u32)f2bf(a) | ((u32)f2bf(b) << 16);
}
__device__ __forceinline__ uint4 cvt8(const float* __restrict__ s) {
  float4 f0 = ((const float4*)s)[0];
  float4 f1 = ((const float4*)s)[1];
  uint4 o;
  o.x = pack2(f0.x, f0.y); o.y = pack2(f0.z, f0.w);
  o.z = pack2(f1.x, f1.y); o.w = pack2(f1.z, f1.w);
  return o;
}

// ---------------------------------------------------------------- prep ----
__global__ void lstm_prep(
    const float* __restrict__ x,
    const float* __restrict__ Whf, const float* __restrict__ Whi,
    const float* __restrict__ Whg, const float* __restrict__ Who,
    const float* __restrict__ Wxf, const float* __restrict__ Wxi,
    const float* __restrict__ Wxg, const float* __restrict__ Wxo,
    const float* __restrict__ bfp, const float* __restrict__ bip,
    const float* __restrict__ bgp, const float* __restrict__ bop,
    const float* __restrict__ Why,
    u16* __restrict__ xt, u16* __restrict__ Wc, float* __restrict__ bc,
    u16* __restrict__ WhyT, u16* __restrict__ hbuf, u32* __restrict__ barrier)
{
  const int gid = blockIdx.x * blockDim.x + threadIdx.x;
  const int gsz = gridDim.x * blockDim.x;

  if (gid < 32) barrier[gid] = 0u;   // zero barrier counter (ws is poisoned)

  // xt[t][b][i] <- x[b][t][i]  (bf16, time-major)
  for (int v = gid; v < (S_ * B_ * I_ / 8); v += gsz) {
    int flat = v * 8;
    int t = flat / (B_ * I_);
    int r = flat - t * (B_ * I_);
    int b = r / I_;
    int i = r - b * I_;
    const float* s = x + (size_t)b * (S_ * I_) + (size_t)t * I_ + i;
    *(uint4*)(xt + flat) = cvt8(s);
  }

  // Wc[n][k]: n = (unit_block<<5) + u_local*4 + gate; k<1024 -> Wh, else Wx
  for (int v = gid; v < (4096 * 1536 / 8); v += gsz) {
    int n = v / 192;
    int k = (v - n * 192) * 8;
    int unit = ((n >> 5) << 3) + ((n >> 2) & 7);
    int g = n & 3;
    const float* Whp = (g == 0) ? Whf : (g == 1) ? Whi : (g == 2) ? Whg : Who;
    const float* Wxp = (g == 0) ? Wxf : (g == 1) ? Wxi : (g == 2) ? Wxg : Wxo;
    const float* s = (k < 1024) ? (Whp + (size_t)unit * 1024 + k)
                                : (Wxp + (size_t)unit * 512 + (k - 1024));
    *(uint4*)(Wc + (size_t)n * 1536 + k) = cvt8(s);
  }

  // bias, gate-interleaved
  for (int n = gid; n < 4096; n += gsz) {
    int unit = ((n >> 5) << 3) + ((n >> 2) & 7);
    int g = n & 3;
    const float* bp = (g == 0) ? bfp : (g == 1) ? bip : (g == 2) ? bgp : bop;
    bc[n] = bp[unit];
  }

  // Why -> bf16 (row-major [o][k])
  for (int v = gid; v < (O_ * H_ / 8); v += gsz) {
    int flat = v * 8;
    *(uint4*)(WhyT + flat) = cvt8(Why + flat);
  }

  // zero both h ping-pong buffers
  for (int v = gid; v < (2 * B_ * H_ / 8); v += gsz) {
    uint4 z; z.x = 0; z.y = 0; z.z = 0; z.w = 0;
    *(uint4*)(hbuf + v * 8) = z;
  }
}

// ------------------------------------------------------ persistent LSTM ----
__global__ __launch_bounds__(256, 1) void lstm_seq(
    const u16* __restrict__ xt, const u16* __restrict__ Wc,
    const float* __restrict__ bc, u16* __restrict__ hbuf,
    const u16* __restrict__ WhyT, const float* __restrict__ WhyB,
    float* __restrict__ out, u32* __restrict__ barrier)
{
  // 64 KiB: this wg's 32 gate-columns of Wh (k<1024), 16B slots, XOR-swizzled:
  // slot(n,kg) = n*128 + (kg ^ (n&7))
  __shared__ uint4 WhLds[4096];

  const int tid  = threadIdx.x;
  const int lane = tid & 63;
  const int w    = tid >> 6;     // wave 0..3, owns batch rows 32w..32w+31
  const int wg   = blockIdx.x;   // 0..127, owns hidden units wg*8..wg*8+7

  for (int s = tid; s < 4096; s += 256) {
    int n = s >> 7;
    int kg = (s & 127) ^ (n & 7);
    WhLds[s] = *(const uint4*)(Wc + ((size_t)(wg * 32 + n)) * 1536 + (size_t)kg * 8);
  }
  __syncthreads();

  const int colN  = lane & 31;          // B n-index / C col (32x32 mfma)
  const int col7  = colN & 7;
  const int kgsel = lane >> 5;
  const int kg8   = kgsel << 3;
  const int rowA  = (w << 5) + colN;    // A m-index
  const int colG  = (wg << 5) + colN;   // global gate-col
  const int unit  = (wg << 3) + (colN >> 2);
  const int gate  = colN & 3;           // 0=f 1=i 2=g 3=o
  const float bias = bc[colG];

  float c[16];
#pragma unroll
  for (int i = 0; i < 16; ++i) c[i] = 0.f;

#pragma unroll 1
  for (int t = 0; t < S_; ++t) {
    const u16* hb = hbuf + (size_t)(t & 1) * (B_ * H_);
    u16* hn = hbuf + (size_t)((t & 1) ^ 1) * (B_ * H_);
    const u16* xb = xt + (size_t)t * (B_ * I_);

    v16f acc0, acc1;   // two chains so MFMA latency pipelines at 1 wave/SIMD
#pragma unroll
    for (int i = 0; i < 16; ++i) { acc0[i] = 0.f; acc1[i] = 0.f; }

    v8s abuf[2][8], bbuf[2][8];

    auto ldx = [&](int kc, v8s& a, v8s& b) {   // kc in [0,32): x-part K chunk
      a = *(const v8s*)(xb + (size_t)rowA * I_ + kc * 16 + kg8);
      b = *(const v8s*)(Wc + (size_t)colG * 1536 + 1024 + kc * 16 + kg8);
    };
    auto ldh = [&](int kc, v8s& a, v8s& b) {   // kc in [0,64): h-part K chunk
      a = *(const v8s*)(hb + (size_t)rowA * H_ + kc * 16 + kg8);
      int kg = kc * 2 + kgsel;
      b = __builtin_bit_cast(v8s, WhLds[(colN << 7) + (kg ^ col7)]);
    };

    // ---- x-part: no dependence on h_{t-1}; runs before the barrier wait ----
#pragma unroll
    for (int j = 0; j < 8; ++j) ldx(j, abuf[0][j], bbuf[0][j]);
#pragma unroll
    for (int g = 0; g < 4; ++g) {
      const int cur = g & 1;
      if (g < 3) {
#pragma unroll
        for (int j = 0; j < 8; ++j)
          ldx((g + 1) * 8 + j, abuf[cur ^ 1][j], bbuf[cur ^ 1][j]);
      }
#pragma unroll
      for (int j = 0; j < 8; j += 2) {
        acc0 = __builtin_amdgcn_mfma_f32_32x32x16_bf16(abuf[cur][j], bbuf[cur][j], acc0, 0, 0, 0);
        acc1 = __builtin_amdgcn_mfma_f32_32x32x16_bf16(abuf[cur][j + 1], bbuf[cur][j + 1], acc1, 0, 0, 0);
      }
    }

    // ---- barrier wait: h_{t-1} ready when count >= 128*t ----
    if (tid == 0) {
      const u32 target = (u32)t * 128u;
      int spins = 0;
      while (__hip_atomic_load(barrier, __ATOMIC_ACQUIRE, __HIP_MEMORY_SCOPE_AGENT) < target) {
        __builtin_amdgcn_s_sleep(2);
        if (++spins > (1 << 24)) break;   // safety valve vs. hang
      }
    }
    __syncthreads();
    __threadfence();   // acquire: drop stale h lines (cross-XCD L2 / L1)

    // ---- h-part ----
#pragma unroll
    for (int j = 0; j < 8; ++j) ldh(j, abuf[0][j], bbuf[0][j]);
#pragma unroll
    for (int g = 0; g < 8; ++g) {
      const int cur = g & 1;
      if (g < 7) {
#pragma unroll
        for (int j = 0; j < 8; ++j)
          ldh((g + 1) * 8 + j, abuf[cur ^ 1][j], bbuf[cur ^ 1][j]);
      }
#pragma unroll
      for (int j = 0; j < 8; j += 2) {
        acc0 = __builtin_amdgcn_mfma_f32_32x32x16_bf16(abuf[cur][j], bbuf[cur][j], acc0, 0, 0, 0);
        acc1 = __builtin_amdgcn_mfma_f32_32x32x16_bf16(abuf[cur][j + 1], bbuf[cur][j + 1], acc1, 0, 0, 0);
      }
    }

    // ---- gates / state update / h write ----
    const bool lastT = (t == S_ - 1);
#pragma unroll
    for (int r = 0; r < 16; ++r) {
      float pre = acc0[r] + acc1[r] + bias;
      // gate 2 -> tanh (overflow-safe), others -> sigmoid
      float e = __expf((gate == 2) ? (2.f * pre) : (-pre));
      float act = (gate == 2) ? (1.f - 2.f / (e + 1.f)) : (1.f / (1.f + e));
      int qb = lane & ~3;   // quad holds f,i,g,o of one (row,unit)
      float F = __shfl(act, qb + 0, 64);
      float I = __shfl(act, qb + 1, 64);
      float G = __shfl(act, qb + 2, 64);
      float O = __shfl(act, qb + 3, 64);
      float cn = fmaf(F, c[r], I * G);
      c[r] = cn;
      float e2 = __expf(2.f * cn);
      float hv = O * (1.f - 2.f / (e2 + 1.f));
      if (gate == 0) {
        int row = (w << 5) + (r & 3) + ((r >> 2) << 3) + (kgsel << 2);
        hn[(size_t)row * H_ + unit] = f2bf(hv);
        if (lastT) {
          out[65536 + row * H_ + unit] = hv;    // h output (fp32)
          out[196608 + row * H_ + unit] = cn;   // c output (fp32)
        }
      }
    }

    // ---- arrive ----
    __threadfence();   // release h writes before bumping the counter
    if (tid == 0)
      __hip_atomic_fetch_add(barrier, 1u, __ATOMIC_RELEASE, __HIP_MEMORY_SCOPE_AGENT);
  }

  // ---- wait for ALL blocks' final h, then out = h_final @ Why^T + b ----
  if (tid == 0) {
    int spins = 0;
    while (__hip_atomic_load(barrier, __ATOMIC_ACQUIRE, __HIP_MEMORY_SCOPE_AGENT) < (u32)(S_ * 128)) {
      __builtin_amdgcn_s_sleep(2);
      if (++spins > (1 << 24)) break;
    }
  }
  __syncthreads();
  __threadfence();

  // final h is in buffer 0 (S_=256 is even)
  if (wg < 32) {
    const u16* hf = hbuf;
    const int l15 = lane & 15;
    const int l4 = lane >> 4;
    const int colO = (wg << 4) + l15;
    v4f o0, o1;
#pragma unroll
    for (int i = 0; i < 4; ++i) { o0[i] = 0.f; o1[i] = 0.f; }
#pragma unroll 4
    for (int kc = 0; kc < 32; ++kc) {
      v8s bfrag = *(const v8s*)(WhyT + (size_t)colO * H_ + kc * 32 + (l4 << 3));
      v8s a0 = *(const v8s*)(hf + (size_t)((w << 5) + l15) * H_ + kc * 32 + (l4 << 3));
      v8s a1 = *(const v8s*)(hf + (size_t)((w << 5) + 16 + l15) * H_ + kc * 32 + (l4 << 3));
      o0 = __builtin_amdgcn_mfma_f32_16x16x32_bf16(a0, bfrag, o0, 0, 0, 0);
      o1 = __builtin_amdgcn_mfma_f32_16x16x32_bf16(a1, bfrag, o1, 0, 0, 0);
    }
    float bO = WhyB[colO];
#pragma unroll
    for (int r = 0; r < 4; ++r) {
      int row = (w << 5) + (l4 << 2) + r;
      out[row * O_ + colO] = o0[r] + bO;
      out[(row + 16) * O_ + colO] = o1[r] + bO;
    }
  }
}

// ------------------------------------------------------------- launch ----
extern "C" void kernel_launch(void* const* d_in, const int* in_sizes, int n_in,
                              void* d_out, int out_size, void* d_ws, size_t ws_size,
                              hipStream_t stream) {
  const float* x    = (const float*)d_in[0];
  const float* Wxf  = (const float*)d_in[1];
  const float* bf_  = (const float*)d_in[2];
  const float* Whf  = (const float*)d_in[3];
  const float* Wxi  = (const float*)d_in[4];
  const float* bi_  = (const float*)d_in[5];
  const float* Whi  = (const float*)d_in[6];
  const float* Wxg  = (const float*)d_in[7];
  const float* bg_  = (const float*)d_in[8];
  const float* Whg  = (const float*)d_in[9];
  const float* Wxo  = (const float*)d_in[10];
  const float* bo_  = (const float*)d_in[11];
  const float* Who  = (const float*)d_in[12];
  const float* Why  = (const float*)d_in[13];
  const float* Whyb = (const float*)d_in[14];

  char* ws = (char*)d_ws;
  u16*   xtp  = (u16*)(ws);                    // 33,554,432 B
  u16*   Wcp  = (u16*)(ws + 33554432);         // 12,582,912 B
  float* bcp  = (float*)(ws + 46137344);       //     16,384 B
  u16*   WhyT = (u16*)(ws + 46153728);         //  1,048,576 B
  u16*   hbuf = (u16*)(ws + 47202304);         //    524,288 B
  u32*   barp = (u32*)(ws + 47726592);         //        128 B  (total ~47.7 MB)
  float* outp = (float*)d_out;

  lstm_prep<<<dim3(1024), dim3(256), 0, stream>>>(
      x, Whf, Whi, Whg, Who, Wxf, Wxi, Wxg, Wxo,
      bf_, bi_, bg_, bo_, Why, xtp, Wcp, bcp, WhyT, hbuf, barp);

  lstm_seq<<<dim3(128), dim3(256), 0, stream>>>(
      xtp, Wcp, bcp, hbuf, WhyT, Whyb, outp, barp);
}

// Round 3
// 6284.389 us; speedup vs baseline: 1.4858x; 1.4858x over previous
//
#include <hip/hip_runtime.h>

// LSTM: B=128, S=256, I=512, H=1024, O=512.
// bf16 MFMA persistent kernel, 128 wgs x 256 thr.
// Grid sync = distributed-slot barrier: block j stores step count to its own
// slot (relaxed agent atomic, no fence side-effects); waiters poll slots with
// RELAXED atomic loads (no per-poll buffer_inv!). Memory ordering is exactly
// one release fence (wbl2) before arrive and one acquire fence (inv) after
// wait, per step. Deadlock-free: 128 blocks < 256 CUs, all co-resident.
// Each wg owns 8 hidden units x 4 gates (32 gate-columns); Wh slice
// (32x1024 bf16 = 64 KiB) lives in LDS for all 256 steps, K-MAJOR layout
// (slot = kg*32 + n) so wave b128 reads are stride-1 => conflict-free.
// Cell state c stays in VGPRs. x-part GEMM (no h dependence) runs BEFORE the
// barrier wait each step to hide barrier latency.

#define B_ 128
#define S_ 256
#define I_ 512
#define H_ 1024
#define O_ 512

typedef unsigned short u16;
typedef unsigned int u32;

typedef short v8s __attribute__((ext_vector_type(8)));   // 8 x bf16 (4 VGPR)
typedef float v16f __attribute__((ext_vector_type(16)));
typedef float v4f __attribute__((ext_vector_type(4)));

__device__ __forceinline__ u16 f2bf(float f) {
  u32 u = __float_as_uint(f);
  u32 r = (u + 0x7fffu + ((u >> 16) & 1u)) >> 16;   // RNE
  return (u16)r;
}
__device__ __forceinline__ u32 pack2(float a, float b) {
  return (u32)f2bf(a) | ((u32)f2bf(b) << 16);
}
__device__ __forceinline__ uint4 cvt8(const float* __restrict__ s) {
  float4 f0 = ((const float4*)s)[0];
  float4 f1 = ((const float4*)s)[1];
  uint4 o;
  o.x = pack2(f0.x, f0.y); o.y = pack2(f0.z, f0.w);
  o.z = pack2(f1.x, f1.y); o.w = pack2(f1.z, f1.w);
  return o;
}

// ---------------------------------------------------------------- prep ----
__global__ void lstm_prep(
    const float* __restrict__ x,
    const float* __restrict__ Whf, const float* __restrict__ Whi,
    const float* __restrict__ Whg, const float* __restrict__ Who,
    const float* __restrict__ Wxf, const float* __restrict__ Wxi,
    const float* __restrict__ Wxg, const float* __restrict__ Wxo,
    const float* __restrict__ bfp, const float* __restrict__ bip,
    const float* __restrict__ bgp, const float* __restrict__ bop,
    const float* __restrict__ Why,
    u16* __restrict__ xt, u16* __restrict__ Wc, float* __restrict__ bc,
    u16* __restrict__ WhyT, u16* __restrict__ hbuf, u32* __restrict__ barrier)
{
  const int gid = blockIdx.x * blockDim.x + threadIdx.x;
  const int gsz = gridDim.x * blockDim.x;

  if (gid < 256) barrier[gid] = 0u;   // zero barrier slots (ws is poisoned)

  // xt[t][b][i] <- x[b][t][i]  (bf16, time-major)
  for (int v = gid; v < (S_ * B_ * I_ / 8); v += gsz) {
    int flat = v * 8;
    int t = flat / (B_ * I_);
    int r = flat - t * (B_ * I_);
    int b = r / I_;
    int i = r - b * I_;
    const float* s = x + (size_t)b * (S_ * I_) + (size_t)t * I_ + i;
    *(uint4*)(xt + flat) = cvt8(s);
  }

  // Wc[n][k]: n = (unit_block<<5) + u_local*4 + gate; k<1024 -> Wh, else Wx
  for (int v = gid; v < (4096 * 1536 / 8); v += gsz) {
    int n = v / 192;
    int k = (v - n * 192) * 8;
    int unit = ((n >> 5) << 3) + ((n >> 2) & 7);
    int g = n & 3;
    const float* Whp = (g == 0) ? Whf : (g == 1) ? Whi : (g == 2) ? Whg : Who;
    const float* Wxp = (g == 0) ? Wxf : (g == 1) ? Wxi : (g == 2) ? Wxg : Wxo;
    const float* s = (k < 1024) ? (Whp + (size_t)unit * 1024 + k)
                                : (Wxp + (size_t)unit * 512 + (k - 1024));
    *(uint4*)(Wc + (size_t)n * 1536 + k) = cvt8(s);
  }

  // bias, gate-interleaved
  for (int n = gid; n < 4096; n += gsz) {
    int unit = ((n >> 5) << 3) + ((n >> 2) & 7);
    int g = n & 3;
    const float* bp = (g == 0) ? bfp : (g == 1) ? bip : (g == 2) ? bgp : bop;
    bc[n] = bp[unit];
  }

  // Why -> bf16 (row-major [o][k])
  for (int v = gid; v < (O_ * H_ / 8); v += gsz) {
    int flat = v * 8;
    *(uint4*)(WhyT + flat) = cvt8(Why + flat);
  }

  // zero both h ping-pong buffers
  for (int v = gid; v < (2 * B_ * H_ / 8); v += gsz) {
    uint4 z; z.x = 0; z.y = 0; z.z = 0; z.w = 0;
    *(uint4*)(hbuf + v * 8) = z;
  }
}

// ------------------------------------------------------ persistent LSTM ----
__global__ __launch_bounds__(256, 1) void lstm_seq(
    const u16* __restrict__ xt, const u16* __restrict__ Wc,
    const float* __restrict__ bc, u16* __restrict__ hbuf,
    const u16* __restrict__ WhyT, const float* __restrict__ WhyB,
    float* __restrict__ out, u32* __restrict__ barrier)
{
  // 64 KiB, K-MAJOR: slot(kg, n) = kg*32 + n  (kg: 16B chunk of K, n: col).
  // Wave read at fixed kg: lanes 0..31 read slots kg*32+0..31 (contiguous
  // 512B), lanes 32..63 read (kg+1)*32+0..31 -> 1 KiB stride-1: conflict-free.
  __shared__ uint4 WhLds[4096];

  const int tid  = threadIdx.x;
  const int lane = tid & 63;
  const int w    = tid >> 6;     // wave 0..3, owns batch rows 32w..32w+31
  const int wg   = blockIdx.x;   // 0..127, owns hidden units wg*8..wg*8+7

  for (int s = tid; s < 4096; s += 256) {
    int kg = s >> 5;
    int n  = s & 31;
    WhLds[s] = *(const uint4*)(Wc + ((size_t)(wg * 32 + n)) * 1536 + (size_t)kg * 8);
  }
  __syncthreads();

  const int colN  = lane & 31;          // B n-index / C col (32x32 mfma)
  const int kgsel = lane >> 5;
  const int kg8   = kgsel << 3;
  const int rowA  = (w << 5) + colN;    // A m-index
  const int colG  = (wg << 5) + colN;   // global gate-col
  const int unit  = (wg << 3) + (colN >> 2);
  const int gate  = colN & 3;           // 0=f 1=i 2=g 3=o
  const float bias = bc[colG];

  float c[16];
#pragma unroll
  for (int i = 0; i < 16; ++i) c[i] = 0.f;

#pragma unroll 1
  for (int t = 0; t < S_; ++t) {
    const u16* hb = hbuf + (size_t)(t & 1) * (B_ * H_);
    u16* hn = hbuf + (size_t)((t & 1) ^ 1) * (B_ * H_);
    const u16* xb = xt + (size_t)t * (B_ * I_);

    v16f acc0, acc1;   // two chains so MFMA latency pipelines at 1 wave/SIMD
#pragma unroll
    for (int i = 0; i < 16; ++i) { acc0[i] = 0.f; acc1[i] = 0.f; }

    v8s abuf[2][8], bbuf[2][8];

    auto ldx = [&](int kc, v8s& a, v8s& b) {   // kc in [0,32): x-part K chunk
      a = *(const v8s*)(xb + (size_t)rowA * I_ + kc * 16 + kg8);
      b = *(const v8s*)(Wc + (size_t)colG * 1536 + 1024 + kc * 16 + kg8);
    };
    auto ldh = [&](int kc, v8s& a, v8s& b) {   // kc in [0,64): h-part K chunk
      a = *(const v8s*)(hb + (size_t)rowA * H_ + kc * 16 + kg8);
      b = __builtin_bit_cast(v8s, WhLds[((kc * 2 + kgsel) << 5) + colN]);
    };

    // ---- x-part: no dependence on h_{t-1}; runs before the barrier wait ----
#pragma unroll
    for (int j = 0; j < 8; ++j) ldx(j, abuf[0][j], bbuf[0][j]);
#pragma unroll
    for (int g = 0; g < 4; ++g) {
      const int cur = g & 1;
      if (g < 3) {
#pragma unroll
        for (int j = 0; j < 8; ++j)
          ldx((g + 1) * 8 + j, abuf[cur ^ 1][j], bbuf[cur ^ 1][j]);
      }
#pragma unroll
      for (int j = 0; j < 8; j += 2) {
        acc0 = __builtin_amdgcn_mfma_f32_32x32x16_bf16(abuf[cur][j], bbuf[cur][j], acc0, 0, 0, 0);
        acc1 = __builtin_amdgcn_mfma_f32_32x32x16_bf16(abuf[cur][j + 1], bbuf[cur][j + 1], acc1, 0, 0, 0);
      }
    }

    // ---- wait: h_{t-1} ready when every block's slot >= t. RELAXED polls
    // (atomic => bypasses L2 to coherence point, but NO per-poll cache inv);
    // one acquire fence after the barrier to drop stale h lines. ----
    if (t > 0) {
      if (tid < 128) {
        u32 spins = 0;
        while (__hip_atomic_load(&barrier[tid], __ATOMIC_RELAXED,
                                 __HIP_MEMORY_SCOPE_AGENT) < (u32)t) {
          __builtin_amdgcn_s_sleep(1);
          if (++spins > (1u << 22)) break;   // safety valve vs. hang
        }
      }
      __syncthreads();
      __builtin_amdgcn_fence(__ATOMIC_ACQUIRE, "agent");
    }

    // ---- h-part ----
#pragma unroll
    for (int j = 0; j < 8; ++j) ldh(j, abuf[0][j], bbuf[0][j]);
#pragma unroll
    for (int g = 0; g < 8; ++g) {
      const int cur = g & 1;
      if (g < 7) {
#pragma unroll
        for (int j = 0; j < 8; ++j)
          ldh((g + 1) * 8 + j, abuf[cur ^ 1][j], bbuf[cur ^ 1][j]);
      }
#pragma unroll
      for (int j = 0; j < 8; j += 2) {
        acc0 = __builtin_amdgcn_mfma_f32_32x32x16_bf16(abuf[cur][j], bbuf[cur][j], acc0, 0, 0, 0);
        acc1 = __builtin_amdgcn_mfma_f32_32x32x16_bf16(abuf[cur][j + 1], bbuf[cur][j + 1], acc1, 0, 0, 0);
      }
    }

    // ---- gates / state update / h write ----
    const bool lastT = (t == S_ - 1);
#pragma unroll
    for (int r = 0; r < 16; ++r) {
      float pre = acc0[r] + acc1[r] + bias;
      // gate 2 -> tanh (overflow-safe), others -> sigmoid
      float e = __expf((gate == 2) ? (2.f * pre) : (-pre));
      float act = (gate == 2) ? (1.f - 2.f / (e + 1.f)) : (1.f / (1.f + e));
      int qb = lane & ~3;   // quad holds f,i,g,o of one (row,unit)
      float F = __shfl(act, qb + 0, 64);
      float I = __shfl(act, qb + 1, 64);
      float G = __shfl(act, qb + 2, 64);
      float O = __shfl(act, qb + 3, 64);
      float cn = fmaf(F, c[r], I * G);
      c[r] = cn;
      float e2 = __expf(2.f * cn);
      float hv = O * (1.f - 2.f / (e2 + 1.f));
      if (gate == 0) {
        int row = (w << 5) + (r & 3) + ((r >> 2) << 3) + (kgsel << 2);
        hn[(size_t)row * H_ + unit] = f2bf(hv);
        if (lastT) {
          out[65536 + row * H_ + unit] = hv;    // h output (fp32)
          out[196608 + row * H_ + unit] = cn;   // c output (fp32)
        }
      }
    }

    // ---- arrive: syncthreads drains every wave's stores into L2; then one
    // release fence (wbl2 pushes ALL dirty lines to coherence point) and a
    // relaxed store to this block's own slot (no same-line contention). ----
    __syncthreads();
    if (tid == 0) {
      __builtin_amdgcn_fence(__ATOMIC_RELEASE, "agent");
      __hip_atomic_store(&barrier[wg], (u32)(t + 1), __ATOMIC_RELAXED,
                         __HIP_MEMORY_SCOPE_AGENT);
    }
  }

  // ---- wait for ALL blocks' final h, then out = h_final @ Why^T + b ----
  if (tid < 128) {
    u32 spins = 0;
    while (__hip_atomic_load(&barrier[tid], __ATOMIC_RELAXED,
                             __HIP_MEMORY_SCOPE_AGENT) < (u32)S_) {
      __builtin_amdgcn_s_sleep(1);
      if (++spins > (1u << 22)) break;
    }
  }
  __syncthreads();
  __builtin_amdgcn_fence(__ATOMIC_ACQUIRE, "agent");

  // final h is in buffer 0 (S_=256 is even)
  if (wg < 32) {
    const u16* hf = hbuf;
    const int l15 = lane & 15;
    const int l4 = lane >> 4;
    const int colO = (wg << 4) + l15;
    v4f o0, o1;
#pragma unroll
    for (int i = 0; i < 4; ++i) { o0[i] = 0.f; o1[i] = 0.f; }
#pragma unroll 4
    for (int kc = 0; kc < 32; ++kc) {
      v8s bfrag = *(const v8s*)(WhyT + (size_t)colO * H_ + kc * 32 + (l4 << 3));
      v8s a0 = *(const v8s*)(hf + (size_t)((w << 5) + l15) * H_ + kc * 32 + (l4 << 3));
      v8s a1 = *(const v8s*)(hf + (size_t)((w << 5) + 16 + l15) * H_ + kc * 32 + (l4 << 3));
      o0 = __builtin_amdgcn_mfma_f32_16x16x32_bf16(a0, bfrag, o0, 0, 0, 0);
      o1 = __builtin_amdgcn_mfma_f32_16x16x32_bf16(a1, bfrag, o1, 0, 0, 0);
    }
    float bO = WhyB[colO];
#pragma unroll
    for (int r = 0; r < 4; ++r) {
      int row = (w << 5) + (l4 << 2) + r;
      out[row * O_ + colO] = o0[r] + bO;
      out[(row + 16) * O_ + colO] = o1[r] + bO;
    }
  }
}

// ------------------------------------------------------------- launch ----
extern "C" void kernel_launch(void* const* d_in, const int* in_sizes, int n_in,
                              void* d_out, int out_size, void* d_ws, size_t ws_size,
                              hipStream_t stream) {
  const float* x    = (const float*)d_in[0];
  const float* Wxf  = (const float*)d_in[1];
  const float* bf_  = (const float*)d_in[2];
  const float* Whf  = (const float*)d_in[3];
  const float* Wxi  = (const float*)d_in[4];
  const float* bi_  = (const float*)d_in[5];
  const float* Whi  = (const float*)d_in[6];
  const float* Wxg  = (const float*)d_in[7];
  const float* bg_  = (const float*)d_in[8];
  const float* Whg  = (const float*)d_in[9];
  const float* Wxo  = (const float*)d_in[10];
  const float* bo_  = (const float*)d_in[11];
  const float* Who  = (const float*)d_in[12];
  const float* Why  = (const float*)d_in[13];
  const float* Whyb = (const float*)d_in[14];

  char* ws = (char*)d_ws;
  u16*   xtp  = (u16*)(ws);                    // 33,554,432 B
  u16*   Wcp  = (u16*)(ws + 33554432);         // 12,582,912 B
  float* bcp  = (float*)(ws + 46137344);       //     16,384 B
  u16*   WhyT = (u16*)(ws + 46153728);         //  1,048,576 B
  u16*   hbuf = (u16*)(ws + 47202304);         //    524,288 B
  u32*   barp = (u32*)(ws + 47726592);         //      1,024 B  (total ~47.7 MB)
  float* outp = (float*)d_out;

  lstm_prep<<<dim3(1024), dim3(256), 0, stream>>>(
      x, Whf, Whi, Whg, Who, Wxf, Wxi, Wxg, Wxo,
      bf_, bi_, bg_, bo_, Why, xtp, Wcp, bcp, WhyT, hbuf, barp);

  lstm_seq<<<dim3(128), dim3(256), 0, stream>>>(
      xtp, Wcp, bcp, hbuf, WhyT, Whyb, outp, barp);
}